// Round 2
// baseline (2220.470 us; speedup 1.0000x reference)
//
#include <hip/hip_runtime.h>

#define NN  100000
#define DEG 32
#define EHD 128
#define FD  16
#define HD  128
#define NT  64   // nodes per block tile

// bank swizzle: row r, col n -> sb[r][n ^ SWZ(r)]
// SWZ uses r>>2 so Phase-A writes (row = 4*cg + d, d fixed per instr) hit 32 distinct banks.
#define SWZ(r) (((r) >> 2) & 31)

using f4v = __attribute__((ext_vector_type(4))) float;

__device__ __forceinline__ void fma_row(float (&acc)[32], float x, const float* __restrict__ wr) {
    #pragma unroll
    for (int t = 0; t < 32; ++t) acc[t] += x * wr[t];
}

__global__ __launch_bounds__(256, 4) void node_mlp_kernel(
    const float* __restrict__ mailbox,
    const float* __restrict__ feat,
    const float* __restrict__ hid,
    const float* __restrict__ W1, const float* __restrict__ b1,
    const float* __restrict__ W2, const float* __restrict__ b2,
    const float* __restrict__ W3, const float* __restrict__ b3,
    float* __restrict__ out)
{
    // single 32 KB buffer, aliased across phases:
    // Phase A: message sums [128 rows][64 nodes]; then h1, h2, out staging.
    __shared__ float sb[EHD][64];

    const int tid   = threadIdx.x;
    const int gbase = blockIdx.x * NT;

    // ---------------- Phase A: mailbox sum (coalesced, nontemporal) ----------------
    {
        const int cg   = tid & 31;   // float4 column group (32 groups x 4 = 128 cols)
        const int nsub = tid >> 5;   // 0..7
        const int c0   = cg << 2;
        for (int k = 0; k < 8; ++k) {
            const int n = nsub + (k << 3);          // 0..63
            const int g = gbase + n;
            float sx = 0.f, sy = 0.f, sz = 0.f, sw = 0.f;
            if (g < NN) {
                const f4v* mb =
                    reinterpret_cast<const f4v*>(mailbox + (size_t)g * (DEG * EHD)) + cg;
                #pragma unroll
                for (int m = 0; m < DEG; ++m) {
                    const f4v v = __builtin_nontemporal_load(mb + m * (EHD / 4));
                    sx += v.x; sy += v.y; sz += v.z; sw += v.w;
                }
            }
            sb[c0 + 0][n ^ SWZ(c0 + 0)] = sx;
            sb[c0 + 1][n ^ SWZ(c0 + 1)] = sy;
            sb[c0 + 2][n ^ SWZ(c0 + 2)] = sz;
            sb[c0 + 3][n ^ SWZ(c0 + 3)] = sw;
        }
    }

    // ---------------- Phase B: fused 3-layer MLP ----------------
    // lane = node within tile; wave owns a 32-wide output column slab (jc uniform)
    const int lane  = tid & 63;
    const int jc    = __builtin_amdgcn_readfirstlane((tid >> 6) << 5);
    const int g     = gbase + lane;
    const bool valid = g < NN;

    // ---- layer 1: x = [msum | feat | hidden] @ W1 + b1, relu ----
    float acc[32];
    #pragma unroll
    for (int t = 0; t < 32; ++t) acc[t] = b1[jc + t];

    // feat/hid parts first: no LDS dependence, loads overlap Phase A + barrier
    {
        const float4* fp = reinterpret_cast<const float4*>(feat + (size_t)g * FD);
        #pragma unroll
        for (int q = 0; q < FD / 4; ++q) {
            float4 v = make_float4(0.f, 0.f, 0.f, 0.f);
            if (valid) v = fp[q];
            const float* wr = W1 + (EHD + q * 4) * HD + jc;
            fma_row(acc, v.x, wr);
            fma_row(acc, v.y, wr + HD);
            fma_row(acc, v.z, wr + 2 * HD);
            fma_row(acc, v.w, wr + 3 * HD);
        }
    }
    {
        const float4* hp = reinterpret_cast<const float4*>(hid + (size_t)g * HD);
        #pragma unroll 2
        for (int q = 0; q < HD / 4; ++q) {
            float4 v = make_float4(0.f, 0.f, 0.f, 0.f);
            if (valid) v = hp[q];
            const float* wr = W1 + (EHD + FD + q * 4) * HD + jc;
            fma_row(acc, v.x, wr);
            fma_row(acc, v.y, wr + HD);
            fma_row(acc, v.z, wr + 2 * HD);
            fma_row(acc, v.w, wr + 3 * HD);
        }
    }

    __syncthreads();   // message sums visible

    #pragma unroll 2
    for (int i = 0; i < EHD; ++i) {
        const float xv = sb[i][lane ^ SWZ(i)];
        fma_row(acc, xv, W1 + i * HD + jc);
    }

    __syncthreads();   // all msum reads done before overwrite
    #pragma unroll
    for (int t = 0; t < 32; ++t)
        sb[jc + t][lane ^ SWZ(jc + t)] = fmaxf(acc[t], 0.f);
    __syncthreads();

    // ---- layer 2: h2 = relu(h1 @ W2 + b2) ----
    float a2[32];
    #pragma unroll
    for (int t = 0; t < 32; ++t) a2[t] = b2[jc + t];
    #pragma unroll 2
    for (int i = 0; i < HD; ++i) {
        const float xv = sb[i][lane ^ SWZ(i)];
        fma_row(a2, xv, W2 + i * HD + jc);
    }
    __syncthreads();
    #pragma unroll
    for (int t = 0; t < 32; ++t)
        sb[jc + t][lane ^ SWZ(jc + t)] = fmaxf(a2[t], 0.f);
    __syncthreads();

    // ---- layer 3: out = h2 @ W3 + b3 ----
    float a3[32];
    #pragma unroll
    for (int t = 0; t < 32; ++t) a3[t] = b3[jc + t];
    #pragma unroll 2
    for (int i = 0; i < HD; ++i) {
        const float xv = sb[i][lane ^ SWZ(i)];
        fma_row(a3, xv, W3 + i * HD + jc);
    }
    __syncthreads();
    #pragma unroll
    for (int t = 0; t < 32; ++t)
        sb[jc + t][lane ^ SWZ(jc + t)] = a3[t];
    __syncthreads();

    // ---------------- coalesced float4 output store via LDS transpose ----------------
    {
        const int cg   = tid & 31;
        const int nsub = tid >> 5;
        const int c0   = cg << 2;
        for (int k = 0; k < 8; ++k) {
            const int n  = nsub + (k << 3);
            const int g2 = gbase + n;
            if (g2 < NN) {
                float4 o;
                o.x = sb[c0 + 0][n ^ SWZ(c0 + 0)];
                o.y = sb[c0 + 1][n ^ SWZ(c0 + 1)];
                o.z = sb[c0 + 2][n ^ SWZ(c0 + 2)];
                o.w = sb[c0 + 3][n ^ SWZ(c0 + 3)];
                reinterpret_cast<float4*>(out + (size_t)g2 * HD)[cg] = o;
            }
        }
    }
}

extern "C" void kernel_launch(void* const* d_in, const int* in_sizes, int n_in,
                              void* d_out, int out_size, void* d_ws, size_t ws_size,
                              hipStream_t stream) {
    const float* mailbox = (const float*)d_in[0];
    const float* feat    = (const float*)d_in[1];
    const float* hid     = (const float*)d_in[2];
    const float* W1      = (const float*)d_in[3];
    const float* b1      = (const float*)d_in[4];
    const float* W2      = (const float*)d_in[5];
    const float* b2      = (const float*)d_in[6];
    const float* W3      = (const float*)d_in[7];
    const float* b3      = (const float*)d_in[8];
    float* out = (float*)d_out;

    const int grid = (NN + NT - 1) / NT;   // 1563 tiles of 64 nodes
    hipLaunchKernelGGL(node_mlp_kernel, dim3(grid), dim3(256), 0, stream,
                       mailbox, feat, hid, W1, b1, W2, b2, W3, b3, out);
}